// Round 2
// baseline (1142.175 us; speedup 1.0000x reference)
//
#include <hip/hip_runtime.h>

#define NN 100000
#define NE 1600000
#define DF 128
#define NC 47
#define NBK ((NN + 255) >> 8)   // 391 buckets of 256 dst nodes

// ---------- bf16 helpers ----------
static __device__ __forceinline__ unsigned short f2bf(float f) {
    unsigned int u = __float_as_uint(f);
    unsigned int r = (u + 0x7FFFu + ((u >> 16) & 1u)) >> 16;   // RNE
    return (unsigned short)r;
}

// ---------------- CSR build (bucketed) ----------------

// histogram of edges per bucket (LDS pre-aggregated)
__global__ __launch_bounds__(256) void k_bcount(const int* __restrict__ dst,
                                                int* __restrict__ bcnt) {
    __shared__ int h[NBK];
    for (int i = threadIdx.x; i < NBK; i += 256) h[i] = 0;
    __syncthreads();
    for (int i = blockIdx.x * 256 + threadIdx.x; i < NE; i += gridDim.x * 256)
        atomicAdd(&h[dst[i] >> 8], 1);
    __syncthreads();
    for (int i = threadIdx.x; i < NBK; i += 256)
        if (h[i]) atomicAdd(&bcnt[i], h[i]);
}

// single-block scan over buckets -> boff (exclusive), bcur (working copy)
__global__ __launch_bounds__(512) void k_bscan(const int* __restrict__ bcnt,
                                               int* __restrict__ boff,
                                               int* __restrict__ bcur) {
    __shared__ int s[512];
    int t = threadIdx.x;
    int v = (t < NBK) ? bcnt[t] : 0;
    s[t] = v;
    __syncthreads();
    for (int o = 1; o < 512; o <<= 1) {
        int u = (t >= o) ? s[t - o] : 0;
        __syncthreads();
        s[t] += u;
        __syncthreads();
    }
    if (t <= NBK) boff[t] = s[t] - ((t < NBK) ? bcnt[t] : 0);
    if (t < NBK)  bcur[t] = s[t] - bcnt[t];
}

// scatter edges into bucket-contiguous pair array
__global__ __launch_bounds__(256) void k_bfill(const int* __restrict__ src,
                                               const int* __restrict__ dst,
                                               int* __restrict__ bcur,
                                               int2* __restrict__ eb) {
    int i = blockIdx.x * 256 + threadIdx.x;
    if (i < NE) {
        int d = dst[i];
        int p = atomicAdd(&bcur[d >> 8], 1);
        eb[p] = make_int2(src[i], d);
    }
}

// per-bucket per-node degree counts via LDS histogram (coalesced store)
__global__ __launch_bounds__(256) void k_fill2a(const int2* __restrict__ eb,
                                                const int* __restrict__ boff,
                                                int* __restrict__ cnt) {
    __shared__ int h[256];
    int b = blockIdx.x, t = threadIdx.x;
    h[t] = 0;
    __syncthreads();
    int beg = boff[b], end = boff[b + 1];
    int base = b << 8;
    for (int e = beg + t; e < end; e += 256)
        atomicAdd(&h[eb[e].y - base], 1);
    __syncthreads();
    int node = base + t;
    if (node < NN) cnt[node] = h[t];
}

// block-level exclusive scan over 1024-chunks; writes block totals
__global__ void k_scan1(int* __restrict__ buf, int* __restrict__ part, int n) {
    __shared__ int s[1024];
    int t = threadIdx.x;
    int i = blockIdx.x * 1024 + t;
    int c = (i < n) ? buf[i] : 0;
    s[t] = c;
    __syncthreads();
    for (int off = 1; off < 1024; off <<= 1) {
        int v = (t >= off) ? s[t - off] : 0;
        __syncthreads();
        s[t] += v;
        __syncthreads();
    }
    if (i < n) buf[i] = s[t] - c;
    if (t == 1023) part[blockIdx.x] = s[t];
}

__global__ void k_scan2(int* part, int np) {
    if (threadIdx.x == 0 && blockIdx.x == 0) {
        int run = 0;
        for (int i = 0; i < np; ++i) { int v = part[i]; part[i] = run; run += v; }
    }
}

__global__ void k_scan3(int* __restrict__ buf, const int* __restrict__ part, int n) {
    int i = blockIdx.x * blockDim.x + threadIdx.x;
    if (i < n) buf[i] += part[i >> 10];
}

// per-bucket CSR fill with LDS cursors: col writes stay in a 16KB L2 window
__global__ __launch_bounds__(256) void k_fill2b(const int2* __restrict__ eb,
                                                const int* __restrict__ boff,
                                                const int* __restrict__ rp,
                                                int* __restrict__ col) {
    __shared__ int cur[256];
    int b = blockIdx.x, t = threadIdx.x;
    int base = b << 8;
    int node = base + t;
    cur[t] = (node < NN) ? rp[node] : 0;
    __syncthreads();
    int beg = boff[b], end = boff[b + 1];
    for (int e = beg + t; e < end; e += 256) {
        int2 p = eb[e];
        int pos = atomicAdd(&cur[p.y - base], 1);
        col[pos] = p.x;
    }
}

// ---------------- cast fp32 -> bf16 ----------------

__global__ __launch_bounds__(256) void k_cast(const float4* __restrict__ in,
                                              ushort4* __restrict__ out, int n4) {
    int i = blockIdx.x * 256 + threadIdx.x;
    if (i < n4) {
        float4 v = in[i];
        ushort4 o;
        o.x = f2bf(v.x); o.y = f2bf(v.y); o.z = f2bf(v.z); o.w = f2bf(v.w);
        out[i] = o;
    }
}

// ---------------- mean-aggregate gather (bf16 input): one wave per node ----------------

__global__ __launch_bounds__(256) void k_gather_bf16(
        const unsigned int* __restrict__ hb,   // [node][64] uints = 128 bf16
        const int* __restrict__ rp, const int* __restrict__ col,
        float* __restrict__ hn) {
    int node = blockIdx.x * 4 + (threadIdx.x >> 6);
    int lane = threadIdx.x & 63;
    if (node >= NN) return;
    int beg = rp[node], end = rp[node + 1];
    float ax0 = 0.f, ay0 = 0.f, ax1 = 0.f, ay1 = 0.f;
    int e = beg;
    for (; e + 2 <= end; e += 2) {
        int s0 = col[e], s1 = col[e + 1];
        unsigned int v0 = hb[(size_t)s0 * 64 + lane];
        unsigned int v1 = hb[(size_t)s1 * 64 + lane];
        ax0 += __uint_as_float(v0 << 16);
        ay0 += __uint_as_float(v0 & 0xFFFF0000u);
        ax1 += __uint_as_float(v1 << 16);
        ay1 += __uint_as_float(v1 & 0xFFFF0000u);
    }
    if (e < end) {
        unsigned int v = hb[(size_t)col[e] * 64 + lane];
        ax0 += __uint_as_float(v << 16);
        ay0 += __uint_as_float(v & 0xFFFF0000u);
    }
    float d = (float)(end - beg);
    float inv = (d > 0.f) ? 1.0f / d : 0.0f;
    float2 o; o.x = (ax0 + ax1) * inv; o.y = (ay0 + ay1) * inv;
    ((float2*)hn)[(size_t)node * 64 + lane] = o;
}

// ---------------- fused GEMM: out = h@Ws + hn@Wn + b (+relu), N=128 ----------------

template<bool RELU, bool STOREB>
__global__ __launch_bounds__(256) void k_gemm128(
        const float* __restrict__ h, const float* __restrict__ hn,
        const float* __restrict__ Ws, const float* __restrict__ Wn,
        const float* __restrict__ bias, float* __restrict__ out,
        ushort4* __restrict__ outb) {
    __shared__ float As[16][68];
    __shared__ float Bs[16][128];
    int t = threadIdx.x;
    int row0 = blockIdx.x * 64;
    int tx = t & 31;
    int ty = t >> 5;
    float acc[8][4];
#pragma unroll
    for (int r = 0; r < 8; ++r)
#pragma unroll
        for (int j = 0; j < 4; ++j) acc[r][j] = 0.f;

    for (int phase = 0; phase < 2; ++phase) {
        const float* A = phase ? hn : h;
        const float* W = phase ? Wn : Ws;
        for (int kc = 0; kc < 128; kc += 16) {
            {
                int r = t >> 2, q = t & 3;
                int row = row0 + r; if (row >= NN) row = NN - 1;
                const float4 av = *(const float4*)&A[(size_t)row * 128 + kc + q * 4];
                As[q * 4 + 0][r] = av.x;
                As[q * 4 + 1][r] = av.y;
                As[q * 4 + 2][r] = av.z;
                As[q * 4 + 3][r] = av.w;
            }
            {
                int kk = t >> 5, c4 = t & 31;
                *(float4*)&Bs[kk][c4 * 4]     = *(const float4*)&W[(size_t)(kc + kk) * 128 + c4 * 4];
                *(float4*)&Bs[kk + 8][c4 * 4] = *(const float4*)&W[(size_t)(kc + kk + 8) * 128 + c4 * 4];
            }
            __syncthreads();
#pragma unroll
            for (int k = 0; k < 16; ++k) {
                float4 a0 = *(const float4*)&As[k][ty * 8];
                float4 a1 = *(const float4*)&As[k][ty * 8 + 4];
                float4 bv = *(const float4*)&Bs[k][tx * 4];
                float a[8] = {a0.x, a0.y, a0.z, a0.w, a1.x, a1.y, a1.z, a1.w};
#pragma unroll
                for (int r = 0; r < 8; ++r) {
                    acc[r][0] += a[r] * bv.x;
                    acc[r][1] += a[r] * bv.y;
                    acc[r][2] += a[r] * bv.z;
                    acc[r][3] += a[r] * bv.w;
                }
            }
            __syncthreads();
        }
    }
    float4 bv = *(const float4*)&bias[tx * 4];
    float bb[4] = {bv.x, bv.y, bv.z, bv.w};
#pragma unroll
    for (int r = 0; r < 8; ++r) {
        int row = row0 + ty * 8 + r;
        if (row < NN) {
            float4 o;
            o.x = acc[r][0] + bb[0];
            o.y = acc[r][1] + bb[1];
            o.z = acc[r][2] + bb[2];
            o.w = acc[r][3] + bb[3];
            if (RELU) {
                o.x = fmaxf(o.x, 0.f); o.y = fmaxf(o.y, 0.f);
                o.z = fmaxf(o.z, 0.f); o.w = fmaxf(o.w, 0.f);
            }
            *(float4*)&out[(size_t)row * 128 + tx * 4] = o;
            if (STOREB) {
                ushort4 ob;
                ob.x = f2bf(o.x); ob.y = f2bf(o.y); ob.z = f2bf(o.z); ob.w = f2bf(o.w);
                outb[(size_t)row * 32 + tx] = ob;
            }
        }
    }
}

// ---------------- layer 2: S = h@Ws2 + b2, T = h@Wn2 (48-padded rows) ----------------

__global__ __launch_bounds__(192) void k_gemm47_dual(
        const float* __restrict__ h,
        const float* __restrict__ Ws, const float* __restrict__ Wn,
        const float* __restrict__ bias,
        float* __restrict__ S, float* __restrict__ T) {
    __shared__ float As[16][68];
    __shared__ float Bs[16][48];
    __shared__ float Bn[16][48];
    int t = threadIdx.x;
    int row0 = blockIdx.x * 64;
    int tx = t % 12;
    int ty = t / 12;
    float accs[4][4], acct[4][4];
#pragma unroll
    for (int r = 0; r < 4; ++r)
#pragma unroll
        for (int j = 0; j < 4; ++j) { accs[r][j] = 0.f; acct[r][j] = 0.f; }

    for (int kc = 0; kc < 128; kc += 16) {
        for (int i = t; i < 256; i += 192) {
            int r = i >> 2, q = i & 3;
            int row = row0 + r; if (row >= NN) row = NN - 1;
            const float4 av = *(const float4*)&h[(size_t)row * 128 + kc + q * 4];
            As[q * 4 + 0][r] = av.x;
            As[q * 4 + 1][r] = av.y;
            As[q * 4 + 2][r] = av.z;
            As[q * 4 + 3][r] = av.w;
        }
        for (int i = t; i < 768; i += 192) {
            int kk = i / 48, c = i % 48;
            Bs[kk][c] = (c < 47) ? Ws[(size_t)(kc + kk) * 47 + c] : 0.0f;
            Bn[kk][c] = (c < 47) ? Wn[(size_t)(kc + kk) * 47 + c] : 0.0f;
        }
        __syncthreads();
#pragma unroll
        for (int k = 0; k < 16; ++k) {
            float4 a = *(const float4*)&As[k][ty * 4];
            float4 bs = *(const float4*)&Bs[k][tx * 4];
            float4 bn = *(const float4*)&Bn[k][tx * 4];
            float av[4] = {a.x, a.y, a.z, a.w};
#pragma unroll
            for (int r = 0; r < 4; ++r) {
                accs[r][0] += av[r] * bs.x; accs[r][1] += av[r] * bs.y;
                accs[r][2] += av[r] * bs.z; accs[r][3] += av[r] * bs.w;
                acct[r][0] += av[r] * bn.x; acct[r][1] += av[r] * bn.y;
                acct[r][2] += av[r] * bn.z; acct[r][3] += av[r] * bn.w;
            }
        }
        __syncthreads();
    }
#pragma unroll
    for (int r = 0; r < 4; ++r) {
        int row = row0 + ty * 4 + r;
        if (row < NN) {
#pragma unroll
            for (int j = 0; j < 4; ++j) {
                int c = tx * 4 + j;
                float bb = (c < 47) ? bias[c] : 0.f;
                S[(size_t)row * 48 + c] = accs[r][j] + bb;
                T[(size_t)row * 48 + c] = acct[r][j];
            }
        }
    }
}

// ---------------- layer-2 aggregate: out = S + mean(T over in-neighbors) ----------------

__global__ __launch_bounds__(256) void k_gather47(
        const float* __restrict__ T, const float* __restrict__ S,
        const int* __restrict__ rp, const int* __restrict__ col,
        float* __restrict__ out) {
    int node = blockIdx.x * 4 + (threadIdx.x >> 6);
    int lane = threadIdx.x & 63;
    if (node >= NN) return;
    int beg = rp[node], end = rp[node + 1];
    float a0 = 0.f, a1 = 0.f;
    if (lane < 48) {
        int e = beg;
        for (; e + 2 <= end; e += 2) {
            a0 += T[(size_t)col[e] * 48 + lane];
            a1 += T[(size_t)col[e + 1] * 48 + lane];
        }
        if (e < end) a0 += T[(size_t)col[e] * 48 + lane];
    }
    float d = (float)(end - beg);
    float inv = (d > 0.f) ? 1.0f / d : 0.0f;
    if (lane < 47)
        out[(size_t)node * 47 + lane] = S[(size_t)node * 48 + lane] + (a0 + a1) * inv;
}

// ---------------- launcher ----------------

static inline size_t align_up(size_t x, size_t a) { return (x + a - 1) / a * a; }

extern "C" void kernel_launch(void* const* d_in, const int* in_sizes, int n_in,
                              void* d_out, int out_size, void* d_ws, size_t ws_size,
                              hipStream_t stream) {
    const float* x   = (const float*)d_in[0];
    const int* src   = (const int*)d_in[1];
    const int* dst   = (const int*)d_in[2];
    const float* Ws0 = (const float*)d_in[3];
    const float* Wn0 = (const float*)d_in[4];
    const float* b0  = (const float*)d_in[5];
    const float* Ws1 = (const float*)d_in[6];
    const float* Wn1 = (const float*)d_in[7];
    const float* b1  = (const float*)d_in[8];
    const float* Ws2 = (const float*)d_in[9];
    const float* Wn2 = (const float*)d_in[10];
    const float* b2  = (const float*)d_in[11];
    float* out = (float*)d_out;

    char* ws = (char*)d_ws;
    size_t off = 0;
    int* row_ptr = (int*)(ws + off); off += (size_t)(NN + 1) * 4;
    int* bcnt    = (int*)(ws + off); off += (size_t)NBK * 4;          // contiguous w/ row_ptr for one memset
    size_t zero_bytes = off;                                          // row_ptr + bcnt
    int* boff    = (int*)(ws + off); off += (size_t)(NBK + 1) * 4;
    int* bcur    = (int*)(ws + off); off += (size_t)NBK * 4;
    int* part    = (int*)(ws + off); off = align_up(off + 256 * 4, 256);
    int* col     = (int*)(ws + off); off = align_up(off + (size_t)NE * 4, 256);
    ushort4* XB  = (ushort4*)(ws + off); off = align_up(off + (size_t)NN * DF * 2, 256);  // bf16, reused as HB
    float* HN    = (float*)(ws + off); off = align_up(off + (size_t)NN * DF * 4, 256);
    float* H     = (float*)(ws + off); off = align_up(off + (size_t)NN * DF * 4, 256);
    int2* eb     = (int2*)H;                    // alias: used only before H is written
    float* S     = HN;                          // alias: used only after HN is dead
    float* T     = HN + (size_t)NN * 48;

    // --- CSR build (bucketed) ---
    hipMemsetAsync(row_ptr, 0, zero_bytes, stream);
    k_bcount<<<512, 256, 0, stream>>>(dst, bcnt);
    k_bscan<<<1, 512, 0, stream>>>(bcnt, boff, bcur);
    k_bfill<<<(NE + 255) / 256, 256, 0, stream>>>(src, dst, bcur, eb);
    k_fill2a<<<NBK, 256, 0, stream>>>(eb, boff, row_ptr);
    int nscan = NN + 1;
    int nb1 = (nscan + 1023) / 1024;
    k_scan1<<<nb1, 1024, 0, stream>>>(row_ptr, part, nscan);
    k_scan2<<<1, 1, 0, stream>>>(part, nb1);
    k_scan3<<<(nscan + 255) / 256, 256, 0, stream>>>(row_ptr, part, nscan);
    k_fill2b<<<NBK, 256, 0, stream>>>(eb, boff, row_ptr, col);

    int ggrid = (NN + 3) / 4;
    int mgrid = (NN + 63) / 64;

    // --- layer 0 ---
    k_cast<<<(NN * DF / 4 + 255) / 256, 256, 0, stream>>>((const float4*)x, XB, NN * DF / 4);
    k_gather_bf16<<<ggrid, 256, 0, stream>>>((const unsigned int*)XB, row_ptr, col, HN);
    k_gemm128<true, true><<<mgrid, 256, 0, stream>>>(x, HN, Ws0, Wn0, b0, H, XB);  // XB now = bf16(H)
    // --- layer 1 ---
    k_gather_bf16<<<ggrid, 256, 0, stream>>>((const unsigned int*)XB, row_ptr, col, HN);
    k_gemm128<true, false><<<mgrid, 256, 0, stream>>>(H, HN, Ws1, Wn1, b1, H, nullptr);
    // --- layer 2 (transform-then-aggregate) ---
    k_gemm47_dual<<<mgrid, 192, 0, stream>>>(H, Ws2, Wn2, b2, S, T);
    k_gather47<<<ggrid, 256, 0, stream>>>(T, S, row_ptr, col, out);
}

// Round 3
// 505.878 us; speedup vs baseline: 2.2578x; 2.2578x over previous
//
#include <hip/hip_runtime.h>

#define NN 100000
#define NE 1600000
#define NBK 391                     // buckets of 256 dst nodes
#define CHUNK 8192
#define NBLK ((NE + CHUNK - 1) / CHUNK)   // 196
#define MPAD 100096                 // NN padded to multiple of 128
#define NCAST4 (NN * 32)            // float4 count for x cast (128 feats / 4)

using bf16x8 = __attribute__((ext_vector_type(8))) short;
using f32x4  = __attribute__((ext_vector_type(4))) float;

static __device__ __forceinline__ unsigned short f2bf(float f) {
    unsigned int u = __float_as_uint(f);
    unsigned int r = (u + 0x7FFFu + ((u >> 16) & 1u)) >> 16;   // RNE
    return (unsigned short)r;
}

// ================= CSR build (atomic-free reservation) =================

__global__ __launch_bounds__(256) void k_hist(const int* __restrict__ dst,
                                              int* __restrict__ ghist) {
    __shared__ int h[NBK];
    int b = blockIdx.x, t = threadIdx.x;
    for (int i = t; i < NBK; i += 256) h[i] = 0;
    __syncthreads();
    int beg = b * CHUNK, end = min(beg + CHUNK, NE);
    for (int i = beg + t; i < end; i += 256)
        atomicAdd(&h[dst[i] >> 8], 1);
    __syncthreads();
    for (int i = t; i < NBK; i += 256) ghist[b * NBK + i] = h[i];
}

__global__ __launch_bounds__(512) void k_basescan(const int* __restrict__ ghist,
                                                  int* __restrict__ boff,
                                                  int* __restrict__ gbase) {
    __shared__ int s[512];
    int t = threadIdx.x;
    int tot = 0;
    if (t < NBK)
        for (int blk = 0; blk < NBLK; ++blk) tot += ghist[blk * NBK + t];
    s[t] = tot;
    __syncthreads();
    for (int o = 1; o < 512; o <<= 1) {
        int u = (t >= o) ? s[t - o] : 0;
        __syncthreads();
        s[t] += u;
        __syncthreads();
    }
    int base = s[t] - tot;                  // exclusive prefix
    if (t <= NBK) boff[t] = base;           // t==NBK -> NE
    if (t < NBK) {
        int run = base;
        for (int blk = 0; blk < NBLK; ++blk) {
            int g = ghist[blk * NBK + t];
            gbase[blk * NBK + t] = run;
            run += g;
        }
    }
}

__global__ __launch_bounds__(256) void k_scatter(const int* __restrict__ src,
                                                 const int* __restrict__ dst,
                                                 const int* __restrict__ gbase,
                                                 unsigned int* __restrict__ eb) {
    __shared__ int cur[NBK];
    int b = blockIdx.x, t = threadIdx.x;
    for (int i = t; i < NBK; i += 256) cur[i] = gbase[b * NBK + i];
    __syncthreads();
    int beg = b * CHUNK, end = min(beg + CHUNK, NE);
    for (int i = beg + t; i < end; i += 256) {
        int d = dst[i];
        int p = atomicAdd(&cur[d >> 8], 1);
        eb[p] = ((unsigned int)(d & 255) << 24) | (unsigned int)src[i];
    }
}

__global__ __launch_bounds__(256) void k_fill2a(const unsigned int* __restrict__ eb,
                                                const int* __restrict__ boff,
                                                int* __restrict__ cnt) {
    __shared__ int h[256];
    int b = blockIdx.x, t = threadIdx.x;
    h[t] = 0;
    __syncthreads();
    int beg = boff[b], end = boff[b + 1];
    for (int e = beg + t; e < end; e += 256)
        atomicAdd(&h[eb[e] >> 24], 1);
    __syncthreads();
    int node = (b << 8) + t;
    if (node < NN) cnt[node] = h[t];
}

__global__ void k_scan1(int* __restrict__ buf, int* __restrict__ part, int n) {
    __shared__ int s[1024];
    int t = threadIdx.x;
    int i = blockIdx.x * 1024 + t;
    int c = (i < n) ? buf[i] : 0;
    s[t] = c;
    __syncthreads();
    for (int off = 1; off < 1024; off <<= 1) {
        int v = (t >= off) ? s[t - off] : 0;
        __syncthreads();
        s[t] += v;
        __syncthreads();
    }
    if (i < n) buf[i] = s[t] - c;
    if (t == 1023) part[blockIdx.x] = s[t];
}

__global__ void k_scan2(int* part, int np) {
    if (threadIdx.x == 0 && blockIdx.x == 0) {
        int run = 0;
        for (int i = 0; i < np; ++i) { int v = part[i]; part[i] = run; run += v; }
    }
}

__global__ void k_scan3(int* __restrict__ buf, const int* __restrict__ part, int n) {
    int i = blockIdx.x * blockDim.x + threadIdx.x;
    if (i < n) buf[i] += part[i >> 10];
}

__global__ __launch_bounds__(256) void k_fill2b(const unsigned int* __restrict__ eb,
                                                const int* __restrict__ boff,
                                                const int* __restrict__ rp,
                                                int* __restrict__ col) {
    __shared__ int cur[256];
    int b = blockIdx.x, t = threadIdx.x;
    int node = (b << 8) + t;
    cur[t] = (node < NN) ? rp[node] : 0;
    __syncthreads();
    int beg = boff[b], end = boff[b + 1];
    for (int e = beg + t; e < end; e += 256) {
        unsigned int p = eb[e];
        int pos = atomicAdd(&cur[p >> 24], 1);
        col[pos] = (int)(p & 0xFFFFFFu);
    }
}

// ================= dtype prep =================

__global__ __launch_bounds__(256) void k_cast(const float4* __restrict__ in,
                                              ushort4* __restrict__ out, int n4) {
    int i = blockIdx.x * 256 + threadIdx.x;
    if (i < n4) {
        float4 v = in[i];
        ushort4 o;
        o.x = f2bf(v.x); o.y = f2bf(v.y); o.z = f2bf(v.z); o.w = f2bf(v.w);
        out[i] = o;
    }
}

__global__ __launch_bounds__(256) void k_bt(const float* __restrict__ Ws,
                                            const float* __restrict__ Wn,
                                            unsigned short* __restrict__ BT) {
    int idx = blockIdx.x * 256 + threadIdx.x;   // 32768 total
    int k = idx >> 7, n = idx & 127;
    float v = (k < 128) ? Ws[k * 128 + n] : Wn[(k - 128) * 128 + n];
    BT[n * 256 + k] = f2bf(v);
}

// ================= mean-aggregate gather (bf16 in, bf16 out) =================

__global__ __launch_bounds__(256) void k_gather_bf16(
        const unsigned int* __restrict__ hb,
        const int* __restrict__ rp, const int* __restrict__ col,
        unsigned int* __restrict__ hnb) {
    int node = blockIdx.x * 4 + (threadIdx.x >> 6);
    int lane = threadIdx.x & 63;
    if (node >= NN) return;
    int beg = rp[node], end = rp[node + 1];
    float ax0 = 0.f, ay0 = 0.f, ax1 = 0.f, ay1 = 0.f;
    int e = beg;
    for (; e + 2 <= end; e += 2) {
        int s0 = col[e], s1 = col[e + 1];
        unsigned int v0 = hb[(size_t)s0 * 64 + lane];
        unsigned int v1 = hb[(size_t)s1 * 64 + lane];
        ax0 += __uint_as_float(v0 << 16);
        ay0 += __uint_as_float(v0 & 0xFFFF0000u);
        ax1 += __uint_as_float(v1 << 16);
        ay1 += __uint_as_float(v1 & 0xFFFF0000u);
    }
    if (e < end) {
        unsigned int v = hb[(size_t)col[e] * 64 + lane];
        ax0 += __uint_as_float(v << 16);
        ay0 += __uint_as_float(v & 0xFFFF0000u);
    }
    float d = (float)(end - beg);
    float inv = (d > 0.f) ? 1.0f / d : 0.0f;
    float ox = (ax0 + ax1) * inv, oy = (ay0 + ay1) * inv;
    hnb[(size_t)node * 64 + lane] = ((unsigned int)f2bf(oy) << 16) | (unsigned int)f2bf(ox);
}

// ================= MFMA GEMM =================

template<bool OUTBF16>
__global__ __launch_bounds__(256, 2) void k_mgemm(
        const unsigned short* __restrict__ A0,
        const unsigned short* __restrict__ A1,
        const unsigned short* __restrict__ BT,
        const float* __restrict__ bias,
        float* __restrict__ outF,
        unsigned short* __restrict__ outB) {
    int t = threadIdx.x;
    int lane = t & 63, wid = t >> 6;
    int wm = wid >> 1, wn = wid & 1;
    int lr = lane & 15, lg = lane >> 4;
    int row0 = blockIdx.x * 128 + wm * 64;
    int colw = wn * 64;
    f32x4 zero = {0.f, 0.f, 0.f, 0.f};
    f32x4 acc[4][4];
#pragma unroll
    for (int a = 0; a < 4; ++a)
#pragma unroll
        for (int b = 0; b < 4; ++b) acc[a][b] = zero;

#pragma unroll
    for (int p = 0; p < 2; ++p) {
        const unsigned short* A = p ? A1 : A0;
        bf16x8 bReg[4][4];
#pragma unroll
        for (int nf = 0; nf < 4; ++nf)
#pragma unroll
            for (int ks = 0; ks < 4; ++ks)
                bReg[nf][ks] = *(const bf16x8*)&BT[(size_t)(colw + nf * 16 + lr) * 256 + p * 128 + ks * 32 + lg * 8];
#pragma unroll
        for (int mf = 0; mf < 4; ++mf) {
            const unsigned short* Ar = A + (size_t)(row0 + mf * 16 + lr) * 128;
            bf16x8 aReg[4];
#pragma unroll
            for (int ks = 0; ks < 4; ++ks)
                aReg[ks] = *(const bf16x8*)&Ar[ks * 32 + lg * 8];
#pragma unroll
            for (int ks = 0; ks < 4; ++ks)
#pragma unroll
                for (int nf = 0; nf < 4; ++nf)
                    acc[mf][nf] = __builtin_amdgcn_mfma_f32_16x16x32_bf16(
                        aReg[ks], bReg[nf][ks], acc[mf][nf], 0, 0, 0);
        }
    }
    __syncthreads();   // A0 may alias outB: all reads drain before in-place writes
#pragma unroll
    for (int nf = 0; nf < 4; ++nf) {
        int cidx = colw + nf * 16 + lr;
        float bb = bias[cidx];
#pragma unroll
        for (int mf = 0; mf < 4; ++mf) {
#pragma unroll
            for (int j = 0; j < 4; ++j) {
                int row = row0 + mf * 16 + lg * 4 + j;
                if (row < NN) {
                    float v = fmaxf(acc[mf][nf][j] + bb, 0.f);
                    if (OUTBF16)
                        outB[(size_t)row * 128 + cidx] = f2bf(v);
                    else
                        outF[(size_t)row * 128 + cidx] = v;
                }
            }
        }
    }
}

// ================= layer 2 (fp32) =================

__global__ __launch_bounds__(192) void k_gemm47_dual(
        const float* __restrict__ h,
        const float* __restrict__ Ws, const float* __restrict__ Wn,
        const float* __restrict__ bias,
        float* __restrict__ S, float* __restrict__ T) {
    __shared__ float As[16][68];
    __shared__ float Bs[16][48];
    __shared__ float Bn[16][48];
    int t = threadIdx.x;
    int row0 = blockIdx.x * 64;
    int tx = t % 12;
    int ty = t / 12;
    float accs[4][4], acct[4][4];
#pragma unroll
    for (int r = 0; r < 4; ++r)
#pragma unroll
        for (int j = 0; j < 4; ++j) { accs[r][j] = 0.f; acct[r][j] = 0.f; }

    for (int kc = 0; kc < 128; kc += 16) {
        for (int i = t; i < 256; i += 192) {
            int r = i >> 2, q = i & 3;
            int row = row0 + r; if (row >= NN) row = NN - 1;
            const float4 av = *(const float4*)&h[(size_t)row * 128 + kc + q * 4];
            As[q * 4 + 0][r] = av.x;
            As[q * 4 + 1][r] = av.y;
            As[q * 4 + 2][r] = av.z;
            As[q * 4 + 3][r] = av.w;
        }
        for (int i = t; i < 768; i += 192) {
            int kk = i / 48, c = i % 48;
            Bs[kk][c] = (c < 47) ? Ws[(size_t)(kc + kk) * 47 + c] : 0.0f;
            Bn[kk][c] = (c < 47) ? Wn[(size_t)(kc + kk) * 47 + c] : 0.0f;
        }
        __syncthreads();
#pragma unroll
        for (int k = 0; k < 16; ++k) {
            float4 a = *(const float4*)&As[k][ty * 4];
            float4 bs = *(const float4*)&Bs[k][tx * 4];
            float4 bn = *(const float4*)&Bn[k][tx * 4];
            float av[4] = {a.x, a.y, a.z, a.w};
#pragma unroll
            for (int r = 0; r < 4; ++r) {
                accs[r][0] += av[r] * bs.x; accs[r][1] += av[r] * bs.y;
                accs[r][2] += av[r] * bs.z; accs[r][3] += av[r] * bs.w;
                acct[r][0] += av[r] * bn.x; acct[r][1] += av[r] * bn.y;
                acct[r][2] += av[r] * bn.z; acct[r][3] += av[r] * bn.w;
            }
        }
        __syncthreads();
    }
#pragma unroll
    for (int r = 0; r < 4; ++r) {
        int row = row0 + ty * 4 + r;
        if (row < NN) {
#pragma unroll
            for (int j = 0; j < 4; ++j) {
                int c = tx * 4 + j;
                float bb = (c < 47) ? bias[c] : 0.f;
                S[(size_t)row * 48 + c] = accs[r][j] + bb;
                T[(size_t)row * 48 + c] = acct[r][j];
            }
        }
    }
}

__global__ __launch_bounds__(256) void k_gather47(
        const float* __restrict__ T, const float* __restrict__ S,
        const int* __restrict__ rp, const int* __restrict__ col,
        float* __restrict__ out) {
    int node = blockIdx.x * 4 + (threadIdx.x >> 6);
    int lane = threadIdx.x & 63;
    if (node >= NN) return;
    int beg = rp[node], end = rp[node + 1];
    float a0 = 0.f, a1 = 0.f;
    if (lane < 48) {
        int e = beg;
        for (; e + 2 <= end; e += 2) {
            a0 += T[(size_t)col[e] * 48 + lane];
            a1 += T[(size_t)col[e + 1] * 48 + lane];
        }
        if (e < end) a0 += T[(size_t)col[e] * 48 + lane];
    }
    float d = (float)(end - beg);
    float inv = (d > 0.f) ? 1.0f / d : 0.0f;
    if (lane < 47)
        out[(size_t)node * 47 + lane] = S[(size_t)node * 48 + lane] + (a0 + a1) * inv;
}

// ================= launcher =================

static inline size_t align_up(size_t x, size_t a) { return (x + a - 1) / a * a; }

extern "C" void kernel_launch(void* const* d_in, const int* in_sizes, int n_in,
                              void* d_out, int out_size, void* d_ws, size_t ws_size,
                              hipStream_t stream) {
    const float* x   = (const float*)d_in[0];
    const int* src   = (const int*)d_in[1];
    const int* dst   = (const int*)d_in[2];
    const float* Ws0 = (const float*)d_in[3];
    const float* Wn0 = (const float*)d_in[4];
    const float* b0  = (const float*)d_in[5];
    const float* Ws1 = (const float*)d_in[6];
    const float* Wn1 = (const float*)d_in[7];
    const float* b1  = (const float*)d_in[8];
    const float* Ws2 = (const float*)d_in[9];
    const float* Wn2 = (const float*)d_in[10];
    const float* b2  = (const float*)d_in[11];
    float* out = (float*)d_out;

    char* ws = (char*)d_ws;
    size_t off = 0;
    auto alloc = [&](size_t bytes) -> void* {
        void* p = ws + off; off = align_up(off + bytes, 256); return p;
    };
    int* row_ptr = (int*)alloc((size_t)(NN + 1) * 4);
    int* boff    = (int*)alloc((size_t)(NBK + 1) * 4);
    int* gbase   = (int*)alloc((size_t)NBLK * NBK * 4);
    int* ghist   = (int*)alloc((size_t)NBLK * NBK * 4);
    int* part    = (int*)alloc(256 * 4);
    int* col     = (int*)alloc((size_t)NE * 4);
    unsigned short* XB  = (unsigned short*)alloc((size_t)MPAD * 128 * 2);
    float* H1    = (float*)alloc((size_t)NN * 128 * 4);
    unsigned short* BT0 = (unsigned short*)alloc(128 * 256 * 2);
    unsigned short* BT1 = (unsigned short*)alloc(128 * 256 * 2);
    char* big = (char*)alloc((size_t)NN * 48 * 4 * 2);   // 38.4MB, time-shared
    unsigned int* eb  = (unsigned int*)big;
    unsigned int* HNB = (unsigned int*)big;
    float* S = (float*)big;
    float* T = S + (size_t)NN * 48;

    // --- CSR build (no global atomics) ---
    k_hist<<<NBLK, 256, 0, stream>>>(dst, ghist);
    k_basescan<<<1, 512, 0, stream>>>(ghist, boff, gbase);
    k_scatter<<<NBLK, 256, 0, stream>>>(src, dst, gbase, eb);
    k_fill2a<<<NBK, 256, 0, stream>>>(eb, boff, row_ptr);
    int nscan = NN + 1;
    int nb1 = (nscan + 1023) / 1024;
    k_scan1<<<nb1, 1024, 0, stream>>>(row_ptr, part, nscan);
    k_scan2<<<1, 1, 0, stream>>>(part, nb1);
    k_scan3<<<(nscan + 255) / 256, 256, 0, stream>>>(row_ptr, part, nscan);
    k_fill2b<<<NBK, 256, 0, stream>>>(eb, boff, row_ptr, col);

    // --- prep ---
    k_cast<<<(NCAST4 + 255) / 256, 256, 0, stream>>>((const float4*)x, (ushort4*)XB, NCAST4);
    k_bt<<<128, 256, 0, stream>>>(Ws0, Wn0, BT0);
    k_bt<<<128, 256, 0, stream>>>(Ws1, Wn1, BT1);

    int ggrid = (NN + 3) / 4;
    int mgrid = MPAD / 128;
    int g47   = (NN + 63) / 64;

    // --- layer 0 (bf16 out, in place over XB) ---
    k_gather_bf16<<<ggrid, 256, 0, stream>>>((const unsigned int*)XB, row_ptr, col, HNB);
    k_mgemm<true><<<mgrid, 256, 0, stream>>>(XB, (const unsigned short*)HNB, BT0, b0, nullptr, XB);
    // --- layer 1 (fp32 out) ---
    k_gather_bf16<<<ggrid, 256, 0, stream>>>((const unsigned int*)XB, row_ptr, col, HNB);
    k_mgemm<false><<<mgrid, 256, 0, stream>>>(XB, (const unsigned short*)HNB, BT1, b1, H1, nullptr);
    // --- layer 2 (fp32 transform-then-aggregate) ---
    k_gemm47_dual<<<g47, 192, 0, stream>>>(H1, Ws2, Wn2, b2, S, T);
    k_gather47<<<ggrid, 256, 0, stream>>>(T, S, row_ptr, col, out);
}

// Round 4
// 408.723 us; speedup vs baseline: 2.7945x; 1.2377x over previous
//
#include <hip/hip_runtime.h>

#define NN 100000
#define NE 1600000
#define NBK 391                     // buckets of 256 dst nodes
#define CHUNK 8192
#define NBLK ((NE + CHUNK - 1) / CHUNK)   // 196
#define MPAD 100096                 // NN padded to multiple of 128
#define NCAST4 (NN * 32)            // float4 count for x cast (128 feats / 4)

using bf16x8 = __attribute__((ext_vector_type(8))) short;
using f32x4  = __attribute__((ext_vector_type(4))) float;

static __device__ __forceinline__ unsigned short f2bf(float f) {
    unsigned int u = __float_as_uint(f);
    unsigned int r = (u + 0x7FFFu + ((u >> 16) & 1u)) >> 16;   // RNE
    return (unsigned short)r;
}
static __device__ __forceinline__ float bf2f(unsigned short b) {
    return __uint_as_float((unsigned int)b << 16);
}

// ================= CSR build (atomic-free reservation) =================

__global__ __launch_bounds__(256) void k_hist(const int* __restrict__ dst,
                                              int* __restrict__ ghist) {
    __shared__ int h[NBK];
    int b = blockIdx.x, t = threadIdx.x;
    for (int i = t; i < NBK; i += 256) h[i] = 0;
    __syncthreads();
    int beg = b * CHUNK, end = min(beg + CHUNK, NE);
    for (int i = beg + t; i < end; i += 256)
        atomicAdd(&h[dst[i] >> 8], 1);
    __syncthreads();
    for (int i = t; i < NBK; i += 256) ghist[b * NBK + i] = h[i];
}

__global__ __launch_bounds__(512) void k_basescan(const int* __restrict__ ghist,
                                                  int* __restrict__ boff,
                                                  int* __restrict__ gbase) {
    __shared__ int s[512];
    int t = threadIdx.x;
    int tot = 0;
    if (t < NBK)
        for (int blk = 0; blk < NBLK; ++blk) tot += ghist[blk * NBK + t];
    s[t] = tot;
    __syncthreads();
    for (int o = 1; o < 512; o <<= 1) {
        int u = (t >= o) ? s[t - o] : 0;
        __syncthreads();
        s[t] += u;
        __syncthreads();
    }
    int base = s[t] - tot;                  // exclusive prefix
    if (t <= NBK) boff[t] = base;
    if (t < NBK) {
        int run = base;
        for (int blk = 0; blk < NBLK; ++blk) {
            int g = ghist[blk * NBK + t];
            gbase[blk * NBK + t] = run;
            run += g;
        }
    }
}

__global__ __launch_bounds__(256) void k_scatter(const int* __restrict__ src,
                                                 const int* __restrict__ dst,
                                                 const int* __restrict__ gbase,
                                                 unsigned int* __restrict__ eb) {
    __shared__ int cur[NBK];
    int b = blockIdx.x, t = threadIdx.x;
    for (int i = t; i < NBK; i += 256) cur[i] = gbase[b * NBK + i];
    __syncthreads();
    int beg = b * CHUNK, end = min(beg + CHUNK, NE);
    for (int i = beg + t; i < end; i += 256) {
        int d = dst[i];
        int p = atomicAdd(&cur[d >> 8], 1);
        eb[p] = ((unsigned int)(d & 255) << 24) | (unsigned int)src[i];
    }
}

__global__ __launch_bounds__(256) void k_fill2a(const unsigned int* __restrict__ eb,
                                                const int* __restrict__ boff,
                                                int* __restrict__ cnt) {
    __shared__ int h[256];
    int b = blockIdx.x, t = threadIdx.x;
    h[t] = 0;
    __syncthreads();
    int beg = boff[b], end = boff[b + 1];
    for (int e = beg + t; e < end; e += 256)
        atomicAdd(&h[eb[e] >> 24], 1);
    __syncthreads();
    int node = (b << 8) + t;
    if (node < NN) cnt[node] = h[t];
}

__global__ void k_scan1(int* __restrict__ buf, int* __restrict__ part, int n) {
    __shared__ int s[1024];
    int t = threadIdx.x;
    int i = blockIdx.x * 1024 + t;
    int c = (i < n) ? buf[i] : 0;
    s[t] = c;
    __syncthreads();
    for (int off = 1; off < 1024; off <<= 1) {
        int v = (t >= off) ? s[t - off] : 0;
        __syncthreads();
        s[t] += v;
        __syncthreads();
    }
    if (i < n) buf[i] = s[t] - c;
    if (t == 1023) part[blockIdx.x] = s[t];
}

__global__ void k_scan2(int* part, int np) {
    if (threadIdx.x == 0 && blockIdx.x == 0) {
        int run = 0;
        for (int i = 0; i < np; ++i) { int v = part[i]; part[i] = run; run += v; }
    }
}

__global__ void k_scan3(int* __restrict__ buf, const int* __restrict__ part, int n) {
    int i = blockIdx.x * blockDim.x + threadIdx.x;
    if (i < n) buf[i] += part[i >> 10];
}

__global__ __launch_bounds__(256) void k_fill2b(const unsigned int* __restrict__ eb,
                                                const int* __restrict__ boff,
                                                const int* __restrict__ rp,
                                                int* __restrict__ col) {
    __shared__ int cur[256];
    int b = blockIdx.x, t = threadIdx.x;
    int node = (b << 8) + t;
    cur[t] = (node < NN) ? rp[node] : 0;
    __syncthreads();
    int beg = boff[b], end = boff[b + 1];
    for (int e = beg + t; e < end; e += 256) {
        unsigned int p = eb[e];
        int pos = atomicAdd(&cur[p >> 24], 1);
        col[pos] = (int)(p & 0xFFFFFFu);
    }
}

// ================= dtype prep =================

__global__ __launch_bounds__(256) void k_cast(const float4* __restrict__ in,
                                              ushort4* __restrict__ out, int n4) {
    int i = blockIdx.x * 256 + threadIdx.x;
    if (i < n4) {
        float4 v = in[i];
        ushort4 o;
        o.x = f2bf(v.x); o.y = f2bf(v.y); o.z = f2bf(v.z); o.w = f2bf(v.w);
        out[i] = o;
    }
}

// BT[n][k] (128 x 256 bf16): k<128 from Ws, k>=128 from Wn
__global__ __launch_bounds__(256) void k_bt(const float* __restrict__ Ws,
                                            const float* __restrict__ Wn,
                                            unsigned short* __restrict__ BT) {
    int idx = blockIdx.x * 256 + threadIdx.x;   // 32768
    int k = idx >> 7, n = idx & 127;
    float v = (k < 128) ? Ws[k * 128 + n] : Wn[(k - 128) * 128 + n];
    BT[n * 256 + k] = f2bf(v);
}

// BT2[n][k] (96 x 128 bf16): n<48 -> Ws2 col n, n>=48 -> Wn2 col n-48 (47-col pad 0)
__global__ __launch_bounds__(256) void k_bt2(const float* __restrict__ Ws,
                                             const float* __restrict__ Wn,
                                             unsigned short* __restrict__ BT2) {
    int idx = blockIdx.x * 256 + threadIdx.x;   // 12288
    if (idx >= 96 * 128) return;
    int n = idx >> 7, k = idx & 127;
    float v = 0.f;
    if (n < 48) { if (n < 47) v = Ws[k * 47 + n]; }
    else        { int c = n - 48; if (c < 47) v = Wn[k * 47 + c]; }
    BT2[n * 128 + k] = f2bf(v);
}

// ================= mean-aggregate gather (bf16 in, bf16 out), unroll-4 =================

__global__ __launch_bounds__(256) void k_gather_bf16(
        const unsigned int* __restrict__ hb,
        const int* __restrict__ rp, const int* __restrict__ col,
        unsigned int* __restrict__ hnb) {
    int node = blockIdx.x * 4 + (threadIdx.x >> 6);
    int lane = threadIdx.x & 63;
    if (node >= NN) return;
    int beg = rp[node], end = rp[node + 1];
    float ax0 = 0.f, ay0 = 0.f, ax1 = 0.f, ay1 = 0.f;
    float ax2 = 0.f, ay2 = 0.f, ax3 = 0.f, ay3 = 0.f;
    int e = beg;
    for (; e + 4 <= end; e += 4) {
        unsigned int v0 = hb[(size_t)col[e]     * 64 + lane];
        unsigned int v1 = hb[(size_t)col[e + 1] * 64 + lane];
        unsigned int v2 = hb[(size_t)col[e + 2] * 64 + lane];
        unsigned int v3 = hb[(size_t)col[e + 3] * 64 + lane];
        ax0 += __uint_as_float(v0 << 16); ay0 += __uint_as_float(v0 & 0xFFFF0000u);
        ax1 += __uint_as_float(v1 << 16); ay1 += __uint_as_float(v1 & 0xFFFF0000u);
        ax2 += __uint_as_float(v2 << 16); ay2 += __uint_as_float(v2 & 0xFFFF0000u);
        ax3 += __uint_as_float(v3 << 16); ay3 += __uint_as_float(v3 & 0xFFFF0000u);
    }
    for (; e < end; ++e) {
        unsigned int v = hb[(size_t)col[e] * 64 + lane];
        ax0 += __uint_as_float(v << 16); ay0 += __uint_as_float(v & 0xFFFF0000u);
    }
    float d = (float)(end - beg);
    float inv = (d > 0.f) ? 1.0f / d : 0.0f;
    float ox = ((ax0 + ax1) + (ax2 + ax3)) * inv;
    float oy = ((ay0 + ay1) + (ay2 + ay3)) * inv;
    hnb[(size_t)node * 64 + lane] = ((unsigned int)f2bf(oy) << 16) | (unsigned int)f2bf(ox);
}

// ================= MFMA GEMM: outB = bf16(relu([A0|A1] @ BT^T + b)) =================

__global__ __launch_bounds__(256, 2) void k_mgemm(
        const unsigned short* __restrict__ A0,
        const unsigned short* __restrict__ A1,
        const unsigned short* __restrict__ BT,
        const float* __restrict__ bias,
        unsigned short* __restrict__ outB) {
    int t = threadIdx.x;
    int lane = t & 63, wid = t >> 6;
    int wm = wid >> 1, wn = wid & 1;
    int lr = lane & 15, lg = lane >> 4;
    int row0 = blockIdx.x * 128 + wm * 64;
    int colw = wn * 64;
    f32x4 zero = {0.f, 0.f, 0.f, 0.f};
    f32x4 acc[4][4];
#pragma unroll
    for (int a = 0; a < 4; ++a)
#pragma unroll
        for (int b = 0; b < 4; ++b) acc[a][b] = zero;

#pragma unroll
    for (int p = 0; p < 2; ++p) {
        const unsigned short* A = p ? A1 : A0;
        bf16x8 bReg[4][4];
#pragma unroll
        for (int nf = 0; nf < 4; ++nf)
#pragma unroll
            for (int ks = 0; ks < 4; ++ks)
                bReg[nf][ks] = *(const bf16x8*)&BT[(size_t)(colw + nf * 16 + lr) * 256 + p * 128 + ks * 32 + lg * 8];
#pragma unroll
        for (int mf = 0; mf < 4; ++mf) {
            const unsigned short* Ar = A + (size_t)(row0 + mf * 16 + lr) * 128;
            bf16x8 aReg[4];
#pragma unroll
            for (int ks = 0; ks < 4; ++ks)
                aReg[ks] = *(const bf16x8*)&Ar[ks * 32 + lg * 8];
#pragma unroll
            for (int ks = 0; ks < 4; ++ks)
#pragma unroll
                for (int nf = 0; nf < 4; ++nf)
                    acc[mf][nf] = __builtin_amdgcn_mfma_f32_16x16x32_bf16(
                        aReg[ks], bReg[nf][ks], acc[mf][nf], 0, 0, 0);
        }
    }
    __syncthreads();   // A0 aliases outB (in-place): drain all reads first
#pragma unroll
    for (int nf = 0; nf < 4; ++nf) {
        int cidx = colw + nf * 16 + lr;
        float bb = bias[cidx];
#pragma unroll
        for (int mf = 0; mf < 4; ++mf) {
#pragma unroll
            for (int j = 0; j < 4; ++j) {
                int row = row0 + mf * 16 + lg * 4 + j;
                if (row < NN) {
                    float v = fmaxf(acc[mf][nf][j] + bb, 0.f);
                    outB[(size_t)row * 128 + cidx] = f2bf(v);
                }
            }
        }
    }
}

// ================= layer 2 MFMA: S = h2@Ws2+b2 (fp32), T = h2@Wn2 (bf16) =================

__global__ __launch_bounds__(256, 2) void k_mgemm47(
        const unsigned short* __restrict__ A,     // [MPAD][128] bf16 h2
        const unsigned short* __restrict__ BT2,   // [96][128]
        const float* __restrict__ bias,           // 47
        float* __restrict__ S,                    // [NN][48] fp32
        unsigned short* __restrict__ TB) {        // [NN][48] bf16
    int t = threadIdx.x;
    int lane = t & 63, wid = t >> 6;
    int wm = wid >> 1, wn = wid & 1;
    int lr = lane & 15, lg = lane >> 4;
    int row0 = blockIdx.x * 128 + wm * 64;
    int colw = wn * 48;
    f32x4 zero = {0.f, 0.f, 0.f, 0.f};
    f32x4 acc[4][3];
#pragma unroll
    for (int a = 0; a < 4; ++a)
#pragma unroll
        for (int b = 0; b < 3; ++b) acc[a][b] = zero;

    bf16x8 bReg[3][4];
#pragma unroll
    for (int nf = 0; nf < 3; ++nf)
#pragma unroll
        for (int ks = 0; ks < 4; ++ks)
            bReg[nf][ks] = *(const bf16x8*)&BT2[(size_t)(colw + nf * 16 + lr) * 128 + ks * 32 + lg * 8];
#pragma unroll
    for (int mf = 0; mf < 4; ++mf) {
        const unsigned short* Ar = A + (size_t)(row0 + mf * 16 + lr) * 128;
        bf16x8 aReg[4];
#pragma unroll
        for (int ks = 0; ks < 4; ++ks)
            aReg[ks] = *(const bf16x8*)&Ar[ks * 32 + lg * 8];
#pragma unroll
        for (int ks = 0; ks < 4; ++ks)
#pragma unroll
            for (int nf = 0; nf < 3; ++nf)
                acc[mf][nf] = __builtin_amdgcn_mfma_f32_16x16x32_bf16(
                    aReg[ks], bReg[nf][ks], acc[mf][nf], 0, 0, 0);
    }
#pragma unroll
    for (int nf = 0; nf < 3; ++nf) {
        int cidx = colw + nf * 16 + lr;      // 0..95
#pragma unroll
        for (int mf = 0; mf < 4; ++mf) {
#pragma unroll
            for (int j = 0; j < 4; ++j) {
                int row = row0 + mf * 16 + lg * 4 + j;
                if (row < NN) {
                    float v = acc[mf][nf][j];
                    if (cidx < 47)
                        S[(size_t)row * 48 + cidx] = v + bias[cidx];
                    else if (cidx >= 48)
                        TB[(size_t)row * 48 + (cidx - 48)] = f2bf(v);
                }
            }
        }
    }
}

// ================= layer-2 aggregate: out = S + mean(TB), unroll-4 =================

__global__ __launch_bounds__(256) void k_gather47b(
        const unsigned short* __restrict__ TB, const float* __restrict__ S,
        const int* __restrict__ rp, const int* __restrict__ col,
        float* __restrict__ out) {
    int node = blockIdx.x * 4 + (threadIdx.x >> 6);
    int lane = threadIdx.x & 63;
    if (node >= NN) return;
    int beg = rp[node], end = rp[node + 1];
    float a0 = 0.f, a1 = 0.f, a2 = 0.f, a3 = 0.f;
    if (lane < 48) {
        int e = beg;
        for (; e + 4 <= end; e += 4) {
            a0 += bf2f(TB[(size_t)col[e]     * 48 + lane]);
            a1 += bf2f(TB[(size_t)col[e + 1] * 48 + lane]);
            a2 += bf2f(TB[(size_t)col[e + 2] * 48 + lane]);
            a3 += bf2f(TB[(size_t)col[e + 3] * 48 + lane]);
        }
        for (; e < end; ++e)
            a0 += bf2f(TB[(size_t)col[e] * 48 + lane]);
    }
    float d = (float)(end - beg);
    float inv = (d > 0.f) ? 1.0f / d : 0.0f;
    if (lane < 47)
        out[(size_t)node * 47 + lane] = S[(size_t)node * 48 + lane] + ((a0 + a1) + (a2 + a3)) * inv;
}

// ================= launcher =================

static inline size_t align_up(size_t x, size_t a) { return (x + a - 1) / a * a; }

extern "C" void kernel_launch(void* const* d_in, const int* in_sizes, int n_in,
                              void* d_out, int out_size, void* d_ws, size_t ws_size,
                              hipStream_t stream) {
    const float* x   = (const float*)d_in[0];
    const int* src   = (const int*)d_in[1];
    const int* dst   = (const int*)d_in[2];
    const float* Ws0 = (const float*)d_in[3];
    const float* Wn0 = (const float*)d_in[4];
    const float* b0  = (const float*)d_in[5];
    const float* Ws1 = (const float*)d_in[6];
    const float* Wn1 = (const float*)d_in[7];
    const float* b1  = (const float*)d_in[8];
    const float* Ws2 = (const float*)d_in[9];
    const float* Wn2 = (const float*)d_in[10];
    const float* b2  = (const float*)d_in[11];
    float* out = (float*)d_out;

    char* ws = (char*)d_ws;
    size_t off = 0;
    auto alloc = [&](size_t bytes) -> void* {
        void* p = ws + off; off = align_up(off + bytes, 256); return p;
    };
    int* row_ptr = (int*)alloc((size_t)(NN + 1) * 4);
    int* boff    = (int*)alloc((size_t)(NBK + 1) * 4);
    int* gbase   = (int*)alloc((size_t)NBLK * NBK * 4);
    int* ghist   = (int*)alloc((size_t)NBLK * NBK * 4);
    int* part    = (int*)alloc(256 * 4);
    int* col     = (int*)alloc((size_t)NE * 4);
    unsigned short* XB  = (unsigned short*)alloc((size_t)MPAD * 128 * 2);
    unsigned short* BT0 = (unsigned short*)alloc(128 * 256 * 2);
    unsigned short* BT1 = (unsigned short*)alloc(128 * 256 * 2);
    unsigned short* BT2 = (unsigned short*)alloc(96 * 128 * 2);
    char* big = (char*)alloc((size_t)NN * 48 * 4 * 2);   // 38.4MB, time-shared
    unsigned int* eb    = (unsigned int*)big;            // CSR build
    unsigned int* HNB   = (unsigned int*)big;            // gathered bf16 rows (25.6MB)
    float* S            = (float*)big;                   // 19.2MB
    unsigned short* TB  = (unsigned short*)(big + (size_t)NN * 48 * 4);  // 9.6MB

    // --- CSR build (no global atomics) ---
    k_hist<<<NBLK, 256, 0, stream>>>(dst, ghist);
    k_basescan<<<1, 512, 0, stream>>>(ghist, boff, gbase);
    k_scatter<<<NBLK, 256, 0, stream>>>(src, dst, gbase, eb);
    k_fill2a<<<NBK, 256, 0, stream>>>(eb, boff, row_ptr);
    int nscan = NN + 1;
    int nb1 = (nscan + 1023) / 1024;
    k_scan1<<<nb1, 1024, 0, stream>>>(row_ptr, part, nscan);
    k_scan2<<<1, 1, 0, stream>>>(part, nb1);
    k_scan3<<<(nscan + 255) / 256, 256, 0, stream>>>(row_ptr, part, nscan);
    k_fill2b<<<NBK, 256, 0, stream>>>(eb, boff, row_ptr, col);

    // --- prep ---
    k_cast<<<(NCAST4 + 255) / 256, 256, 0, stream>>>((const float4*)x, (ushort4*)XB, NCAST4);
    k_bt<<<128, 256, 0, stream>>>(Ws0, Wn0, BT0);
    k_bt<<<128, 256, 0, stream>>>(Ws1, Wn1, BT1);
    k_bt2<<<48, 256, 0, stream>>>(Ws2, Wn2, BT2);

    int ggrid = (NN + 3) / 4;
    int mgrid = MPAD / 128;

    // --- layer 0 (bf16 in-place over XB) ---
    k_gather_bf16<<<ggrid, 256, 0, stream>>>((const unsigned int*)XB, row_ptr, col, HNB);
    k_mgemm<<<mgrid, 256, 0, stream>>>(XB, (const unsigned short*)HNB, BT0, b0, XB);
    // --- layer 1 (bf16 in-place over XB) ---
    k_gather_bf16<<<ggrid, 256, 0, stream>>>((const unsigned int*)XB, row_ptr, col, HNB);
    k_mgemm<<<mgrid, 256, 0, stream>>>(XB, (const unsigned short*)HNB, BT1, b1, XB);
    // --- layer 2 (MFMA transform, bf16 T, fp32 S) ---
    k_mgemm47<<<mgrid, 256, 0, stream>>>(XB, BT2, b2, S, TB);
    k_gather47b<<<ggrid, 256, 0, stream>>>(TB, S, row_ptr, col, out);
}

// Round 5
// 363.410 us; speedup vs baseline: 3.1429x; 1.1247x over previous
//
#include <hip/hip_runtime.h>

#define NN 100000
#define NE 1600000
#define NBK 391                     // buckets of 256 dst nodes
#define CHUNK 8192
#define NBLK ((NE + CHUNK - 1) / CHUNK)   // 196
#define MPAD 100096                 // NN padded to multiple of 128
#define NCAST4 (NN * 32)            // float4 count for x cast
#define CASTB 12500                 // NCAST4 / 256
#define GBLK 2048                   // gather blocks (8192 waves)
#define NPW ((NN + 8191) / 8192)    // nodes per wave = 13

using bf16x8 = __attribute__((ext_vector_type(8))) short;
using f32x4  = __attribute__((ext_vector_type(4))) float;

static __device__ __forceinline__ unsigned short f2bf(float f) {
    unsigned int u = __float_as_uint(f);
    unsigned int r = (u + 0x7FFFu + ((u >> 16) & 1u)) >> 16;   // RNE
    return (unsigned short)r;
}
static __device__ __forceinline__ float lo16(unsigned int u) {
    return __uint_as_float(u << 16);
}
static __device__ __forceinline__ float hi16(unsigned int u) {
    return __uint_as_float(u & 0xFFFF0000u);
}

// ================= CSR build =================

__global__ __launch_bounds__(256) void k_hist(const int* __restrict__ dst,
                                              int* __restrict__ ghist) {
    __shared__ int h[NBK];
    int b = blockIdx.x, t = threadIdx.x;
    for (int i = t; i < NBK; i += 256) h[i] = 0;
    __syncthreads();
    int beg = b * CHUNK, end = min(beg + CHUNK, NE);
    for (int i = beg + t; i < end; i += 256)
        atomicAdd(&h[dst[i] >> 8], 1);
    __syncthreads();
    for (int i = t; i < NBK; i += 256) ghist[b * NBK + i] = h[i];
}

__global__ __launch_bounds__(512) void k_basescan(const int* __restrict__ ghist,
                                                  int* __restrict__ boff,
                                                  int* __restrict__ gbase) {
    __shared__ int s[512];
    int t = threadIdx.x;
    int tot = 0;
    if (t < NBK)
        for (int blk = 0; blk < NBLK; ++blk) tot += ghist[blk * NBK + t];
    s[t] = tot;
    __syncthreads();
    for (int o = 1; o < 512; o <<= 1) {
        int u = (t >= o) ? s[t - o] : 0;
        __syncthreads();
        s[t] += u;
        __syncthreads();
    }
    int base = s[t] - tot;
    if (t <= NBK) boff[t] = base;
    if (t < NBK) {
        int run = base;
        for (int blk = 0; blk < NBLK; ++blk) {
            int g = ghist[blk * NBK + t];
            gbase[blk * NBK + t] = run;
            run += g;
        }
    }
}

__global__ __launch_bounds__(256) void k_scatter(const int* __restrict__ src,
                                                 const int* __restrict__ dst,
                                                 const int* __restrict__ gbase,
                                                 unsigned int* __restrict__ eb) {
    __shared__ int cur[NBK];
    int b = blockIdx.x, t = threadIdx.x;
    for (int i = t; i < NBK; i += 256) cur[i] = gbase[b * NBK + i];
    __syncthreads();
    int beg = b * CHUNK, end = min(beg + CHUNK, NE);
    for (int i = beg + t; i < end; i += 256) {
        int d = dst[i];
        int p = atomicAdd(&cur[d >> 8], 1);
        eb[p] = ((unsigned int)(d & 255) << 24) | (unsigned int)src[i];
    }
}

// fused: per-bucket degree hist -> LDS scan -> row_ptr -> col fill
__global__ __launch_bounds__(256) void k_csr(const unsigned int* __restrict__ eb,
                                             const int* __restrict__ boff,
                                             int* __restrict__ rp,
                                             int* __restrict__ col) {
    __shared__ int h[256];
    __shared__ int sc[256];
    __shared__ int cur[256];
    int b = blockIdx.x, t = threadIdx.x;
    h[t] = 0;
    __syncthreads();
    int beg = boff[b], end = boff[b + 1];
    for (int e = beg + t; e < end; e += 256)
        atomicAdd(&h[eb[e] >> 24], 1);
    __syncthreads();
    int c = h[t];
    sc[t] = c;
    __syncthreads();
    for (int o = 1; o < 256; o <<= 1) {
        int v = (t >= o) ? sc[t - o] : 0;
        __syncthreads();
        sc[t] += v;
        __syncthreads();
    }
    int excl = beg + sc[t] - c;           // global row offset for this node
    int node = (b << 8) + t;
    if (node < NN) rp[node] = excl;
    if (node == NN - 1) rp[NN] = NE;
    cur[t] = excl;
    __syncthreads();
    for (int e = beg + t; e < end; e += 256) {
        unsigned int p = eb[e];
        int pos = atomicAdd(&cur[p >> 24], 1);
        col[pos] = (int)(p & 0xFFFFFFu);
    }
}

// ================= fused prep: cast x->bf16, build BT0/BT1/BT2 =================

__global__ __launch_bounds__(256) void k_prep(
        const float4* __restrict__ x4, ushort4* __restrict__ XB4,
        const float* __restrict__ Ws0, const float* __restrict__ Wn0,
        unsigned short* __restrict__ BT0,
        const float* __restrict__ Ws1, const float* __restrict__ Wn1,
        unsigned short* __restrict__ BT1,
        const float* __restrict__ Ws2, const float* __restrict__ Wn2,
        unsigned short* __restrict__ BT2) {
    int bid = blockIdx.x, t = threadIdx.x;
    if (bid < CASTB) {
        int i = bid * 256 + t;
        float4 v = x4[i];
        ushort4 o;
        o.x = f2bf(v.x); o.y = f2bf(v.y); o.z = f2bf(v.z); o.w = f2bf(v.w);
        XB4[i] = o;
    } else if (bid < CASTB + 128) {
        int idx = (bid - CASTB) * 256 + t;
        int k = idx >> 7, n = idx & 127;
        float v = (k < 128) ? Ws0[k * 128 + n] : Wn0[(k - 128) * 128 + n];
        BT0[n * 256 + k] = f2bf(v);
    } else if (bid < CASTB + 256) {
        int idx = (bid - CASTB - 128) * 256 + t;
        int k = idx >> 7, n = idx & 127;
        float v = (k < 128) ? Ws1[k * 128 + n] : Wn1[(k - 128) * 128 + n];
        BT1[n * 256 + k] = f2bf(v);
    } else {
        int idx = (bid - CASTB - 256) * 256 + t;
        if (idx < 96 * 128) {
            int n = idx >> 7, k = idx & 127;
            float v = 0.f;
            if (n < 48) { if (n < 47) v = Ws2[k * 47 + n]; }
            else        { int cc = n - 48; if (cc < 47) v = Wn2[k * 47 + cc]; }
            BT2[n * 128 + k] = f2bf(v);
        }
    }
}

// ======== mean-aggregate gather 128-feat: grid-strided, 2 edges/load ========

__global__ __launch_bounds__(256) void k_gather128(
        const uint2* __restrict__ hb2,   // [node][32] uint2 (256B bf16 rows)
        const int* __restrict__ rp, const int* __restrict__ col,
        uint2* __restrict__ hnb2) {
    int wave = blockIdx.x * 4 + (threadIdx.x >> 6);
    int lane = threadIdx.x & 63;
    int half = lane >> 5, l32 = lane & 31;
    int n0 = wave * NPW;
    int n1 = min(n0 + NPW, NN);
    for (int node = n0; node < n1; ++node) {
        int beg = rp[node], end = rp[node + 1];
        float a0 = 0.f, a1 = 0.f, a2 = 0.f, a3 = 0.f;
        float b0 = 0.f, b1 = 0.f, b2 = 0.f, b3 = 0.f;
        int e = beg;
        for (; e + 8 <= end; e += 8) {
            int c0 = col[e + half];
            int c1 = col[e + 2 + half];
            int c2 = col[e + 4 + half];
            int c3 = col[e + 6 + half];
            uint2 v0 = hb2[(size_t)c0 * 32 + l32];
            uint2 v1 = hb2[(size_t)c1 * 32 + l32];
            uint2 v2 = hb2[(size_t)c2 * 32 + l32];
            uint2 v3 = hb2[(size_t)c3 * 32 + l32];
            a0 += lo16(v0.x); a1 += hi16(v0.x); a2 += lo16(v0.y); a3 += hi16(v0.y);
            b0 += lo16(v1.x); b1 += hi16(v1.x); b2 += lo16(v1.y); b3 += hi16(v1.y);
            a0 += lo16(v2.x); a1 += hi16(v2.x); a2 += lo16(v2.y); a3 += hi16(v2.y);
            b0 += lo16(v3.x); b1 += hi16(v3.x); b2 += lo16(v3.y); b3 += hi16(v3.y);
        }
        for (; e < end; e += 2) {
            if (e + half < end) {
                uint2 v = hb2[(size_t)col[e + half] * 32 + l32];
                a0 += lo16(v.x); a1 += hi16(v.x); a2 += lo16(v.y); a3 += hi16(v.y);
            }
        }
        float s0 = a0 + b0, s1 = a1 + b1, s2 = a2 + b2, s3 = a3 + b3;
        s0 += __shfl_xor(s0, 32);
        s1 += __shfl_xor(s1, 32);
        s2 += __shfl_xor(s2, 32);
        s3 += __shfl_xor(s3, 32);
        if (half == 0) {
            float d = (float)(end - beg);
            float inv = (d > 0.f) ? 1.0f / d : 0.0f;
            uint2 o;
            o.x = ((unsigned int)f2bf(s1 * inv) << 16) | (unsigned int)f2bf(s0 * inv);
            o.y = ((unsigned int)f2bf(s3 * inv) << 16) | (unsigned int)f2bf(s2 * inv);
            hnb2[(size_t)node * 32 + l32] = o;
        }
    }
}

// ================= MFMA GEMM: outB = bf16(relu([A0|A1] @ BT^T + b)) =================

__global__ __launch_bounds__(256, 2) void k_mgemm(
        const unsigned short* __restrict__ A0,
        const unsigned short* __restrict__ A1,
        const unsigned short* __restrict__ BT,
        const float* __restrict__ bias,
        unsigned short* __restrict__ outB) {
    int t = threadIdx.x;
    int lane = t & 63, wid = t >> 6;
    int wm = wid >> 1, wn = wid & 1;
    int lr = lane & 15, lg = lane >> 4;
    int row0 = blockIdx.x * 128 + wm * 64;
    int colw = wn * 64;
    f32x4 zero = {0.f, 0.f, 0.f, 0.f};
    f32x4 acc[4][4];
#pragma unroll
    for (int a = 0; a < 4; ++a)
#pragma unroll
        for (int b = 0; b < 4; ++b) acc[a][b] = zero;

#pragma unroll
    for (int p = 0; p < 2; ++p) {
        const unsigned short* A = p ? A1 : A0;
        bf16x8 bReg[4][4];
#pragma unroll
        for (int nf = 0; nf < 4; ++nf)
#pragma unroll
            for (int ks = 0; ks < 4; ++ks)
                bReg[nf][ks] = *(const bf16x8*)&BT[(size_t)(colw + nf * 16 + lr) * 256 + p * 128 + ks * 32 + lg * 8];
#pragma unroll
        for (int mf = 0; mf < 4; ++mf) {
            const unsigned short* Ar = A + (size_t)(row0 + mf * 16 + lr) * 128;
            bf16x8 aReg[4];
#pragma unroll
            for (int ks = 0; ks < 4; ++ks)
                aReg[ks] = *(const bf16x8*)&Ar[ks * 32 + lg * 8];
#pragma unroll
            for (int ks = 0; ks < 4; ++ks)
#pragma unroll
                for (int nf = 0; nf < 4; ++nf)
                    acc[mf][nf] = __builtin_amdgcn_mfma_f32_16x16x32_bf16(
                        aReg[ks], bReg[nf][ks], acc[mf][nf], 0, 0, 0);
        }
    }
    __syncthreads();   // A0 aliases outB (in-place): drain all reads first
#pragma unroll
    for (int nf = 0; nf < 4; ++nf) {
        int cidx = colw + nf * 16 + lr;
        float bb = bias[cidx];
#pragma unroll
        for (int mf = 0; mf < 4; ++mf) {
#pragma unroll
            for (int j = 0; j < 4; ++j) {
                int row = row0 + mf * 16 + lg * 4 + j;
                if (row < NN) {
                    float v = fmaxf(acc[mf][nf][j] + bb, 0.f);
                    outB[(size_t)row * 128 + cidx] = f2bf(v);
                }
            }
        }
    }
}

// ====== layer 2 MFMA: S = h2@Ws2+b2 (fp32), T = h2@Wn2 (bf16), BN=96 ======

__global__ __launch_bounds__(256, 2) void k_mgemm47(
        const unsigned short* __restrict__ A,
        const unsigned short* __restrict__ BT2,
        const float* __restrict__ bias,
        float* __restrict__ S,
        unsigned short* __restrict__ TB) {
    int t = threadIdx.x;
    int lane = t & 63, wid = t >> 6;
    int wm = wid >> 1, wn = wid & 1;
    int lr = lane & 15, lg = lane >> 4;
    int row0 = blockIdx.x * 128 + wm * 64;
    int colw = wn * 48;
    f32x4 zero = {0.f, 0.f, 0.f, 0.f};
    f32x4 acc[4][3];
#pragma unroll
    for (int a = 0; a < 4; ++a)
#pragma unroll
        for (int b = 0; b < 3; ++b) acc[a][b] = zero;

    bf16x8 bReg[3][4];
#pragma unroll
    for (int nf = 0; nf < 3; ++nf)
#pragma unroll
        for (int ks = 0; ks < 4; ++ks)
            bReg[nf][ks] = *(const bf16x8*)&BT2[(size_t)(colw + nf * 16 + lr) * 128 + ks * 32 + lg * 8];
#pragma unroll
    for (int mf = 0; mf < 4; ++mf) {
        const unsigned short* Ar = A + (size_t)(row0 + mf * 16 + lr) * 128;
        bf16x8 aReg[4];
#pragma unroll
        for (int ks = 0; ks < 4; ++ks)
            aReg[ks] = *(const bf16x8*)&Ar[ks * 32 + lg * 8];
#pragma unroll
        for (int ks = 0; ks < 4; ++ks)
#pragma unroll
            for (int nf = 0; nf < 3; ++nf)
                acc[mf][nf] = __builtin_amdgcn_mfma_f32_16x16x32_bf16(
                    aReg[ks], bReg[nf][ks], acc[mf][nf], 0, 0, 0);
    }
#pragma unroll
    for (int nf = 0; nf < 3; ++nf) {
        int cidx = colw + nf * 16 + lr;      // 0..95
#pragma unroll
        for (int mf = 0; mf < 4; ++mf) {
#pragma unroll
            for (int j = 0; j < 4; ++j) {
                int row = row0 + mf * 16 + lg * 4 + j;
                if (row < NN) {
                    float v = acc[mf][nf][j];
                    if (cidx < 47)
                        S[(size_t)row * 48 + cidx] = v + bias[cidx];
                    else if (cidx >= 48)
                        TB[(size_t)row * 48 + (cidx - 48)] = f2bf(v);
                }
            }
        }
    }
}

// ======== layer-2 aggregate: out = S + mean(TB), grid-strided, 2 edges/load ========

__global__ __launch_bounds__(256) void k_gather47(
        const unsigned int* __restrict__ TB32,   // [node][24] uint (96B bf16 rows)
        const float2* __restrict__ S2,           // [node][24] float2
        const int* __restrict__ rp, const int* __restrict__ col,
        float* __restrict__ out) {
    int wave = blockIdx.x * 4 + (threadIdx.x >> 6);
    int lane = threadIdx.x & 63;
    int half = lane >> 5, l32 = lane & 31;
    bool act = l32 < 24;
    int n0 = wave * NPW;
    int n1 = min(n0 + NPW, NN);
    for (int node = n0; node < n1; ++node) {
        int beg = rp[node], end = rp[node + 1];
        float c0a = 0.f, c1a = 0.f, c0b = 0.f, c1b = 0.f;
        int e = beg;
        for (; e + 8 <= end; e += 8) {
            int i0 = col[e + half];
            int i1 = col[e + 2 + half];
            int i2 = col[e + 4 + half];
            int i3 = col[e + 6 + half];
            if (act) {
                unsigned int u0 = TB32[(size_t)i0 * 24 + l32];
                unsigned int u1 = TB32[(size_t)i1 * 24 + l32];
                unsigned int u2 = TB32[(size_t)i2 * 24 + l32];
                unsigned int u3 = TB32[(size_t)i3 * 24 + l32];
                c0a += lo16(u0); c1a += hi16(u0);
                c0b += lo16(u1); c1b += hi16(u1);
                c0a += lo16(u2); c1a += hi16(u2);
                c0b += lo16(u3); c1b += hi16(u3);
            }
        }
        for (; e < end; e += 2) {
            if (act && e + half < end) {
                unsigned int u = TB32[(size_t)col[e + half] * 24 + l32];
                c0a += lo16(u); c1a += hi16(u);
            }
        }
        float s0 = c0a + c0b, s1 = c1a + c1b;
        s0 += __shfl_xor(s0, 32);
        s1 += __shfl_xor(s1, 32);
        if (half == 0 && act) {
            float d = (float)(end - beg);
            float inv = (d > 0.f) ? 1.0f / d : 0.0f;
            float2 sv = S2[(size_t)node * 24 + l32];
            int c = l32 * 2;
            out[(size_t)node * 47 + c] = sv.x + s0 * inv;
            if (c + 1 < 47) out[(size_t)node * 47 + c + 1] = sv.y + s1 * inv;
        }
    }
}

// ================= launcher =================

static inline size_t align_up(size_t x, size_t a) { return (x + a - 1) / a * a; }

extern "C" void kernel_launch(void* const* d_in, const int* in_sizes, int n_in,
                              void* d_out, int out_size, void* d_ws, size_t ws_size,
                              hipStream_t stream) {
    const float* x   = (const float*)d_in[0];
    const int* src   = (const int*)d_in[1];
    const int* dst   = (const int*)d_in[2];
    const float* Ws0 = (const float*)d_in[3];
    const float* Wn0 = (const float*)d_in[4];
    const float* b0  = (const float*)d_in[5];
    const float* Ws1 = (const float*)d_in[6];
    const float* Wn1 = (const float*)d_in[7];
    const float* b1  = (const float*)d_in[8];
    const float* Ws2 = (const float*)d_in[9];
    const float* Wn2 = (const float*)d_in[10];
    const float* b2  = (const float*)d_in[11];
    float* out = (float*)d_out;

    char* ws = (char*)d_ws;
    size_t off = 0;
    auto alloc = [&](size_t bytes) -> void* {
        void* p = ws + off; off = align_up(off + bytes, 256); return p;
    };
    int* row_ptr = (int*)alloc((size_t)(NN + 1) * 4);
    int* boff    = (int*)alloc((size_t)(NBK + 1) * 4);
    int* gbase   = (int*)alloc((size_t)NBLK * NBK * 4);
    int* ghist   = (int*)alloc((size_t)NBLK * NBK * 4);
    int* col     = (int*)alloc((size_t)NE * 4);
    unsigned short* XB  = (unsigned short*)alloc((size_t)MPAD * 128 * 2);
    unsigned short* BT0 = (unsigned short*)alloc(128 * 256 * 2);
    unsigned short* BT1 = (unsigned short*)alloc(128 * 256 * 2);
    unsigned short* BT2 = (unsigned short*)alloc(96 * 128 * 2);
    char* big = (char*)alloc((size_t)NN * 48 * 4 * 2);   // 38.4MB, time-shared
    unsigned int* eb    = (unsigned int*)big;            // CSR build
    unsigned int* HNB   = (unsigned int*)big;            // gathered bf16 rows
    float* S            = (float*)big;
    unsigned short* TB  = (unsigned short*)(big + (size_t)NN * 48 * 4);

    // --- CSR build (4 kernels, no global atomics) ---
    k_hist<<<NBLK, 256, 0, stream>>>(dst, ghist);
    k_basescan<<<1, 512, 0, stream>>>(ghist, boff, gbase);
    k_scatter<<<NBLK, 256, 0, stream>>>(src, dst, gbase, eb);
    k_csr<<<NBK, 256, 0, stream>>>(eb, boff, row_ptr, col);

    // --- fused prep: cast + all weight transposes ---
    k_prep<<<CASTB + 256 + 48, 256, 0, stream>>>(
        (const float4*)x, (ushort4*)XB, Ws0, Wn0, BT0, Ws1, Wn1, BT1, Ws2, Wn2, BT2);

    int mgrid = MPAD / 128;

    // --- layer 0 (bf16 in-place over XB) ---
    k_gather128<<<GBLK, 256, 0, stream>>>((const uint2*)XB, row_ptr, col, (uint2*)HNB);
    k_mgemm<<<mgrid, 256, 0, stream>>>(XB, (const unsigned short*)HNB, BT0, b0, XB);
    // --- layer 1 (bf16 in-place over XB) ---
    k_gather128<<<GBLK, 256, 0, stream>>>((const uint2*)XB, row_ptr, col, (uint2*)HNB);
    k_mgemm<<<mgrid, 256, 0, stream>>>(XB, (const unsigned short*)HNB, BT1, b1, XB);
    // --- layer 2 ---
    k_mgemm47<<<mgrid, 256, 0, stream>>>(XB, BT2, b2, S, TB);
    k_gather47<<<GBLK, 256, 0, stream>>>((const unsigned int*)TB, (const float2*)S,
                                         row_ptr, col, out);
}